// Round 1
// baseline (99.398 us; speedup 1.0000x reference)
//
#include <hip/hip_runtime.h>
#include <stdint.h>

// CVKAN layer: out[b,o] = Re( sum_{i,k} basis[b,i,k] * coeffs[i,o,k] + bias[o] )
// basis[b,i,k<8]  = exp(-((x_re[b,i]-g_k)/h)^2)
// basis[b,i,k>=8] = exp(-((x_im[b,i]-g_{k-8})/h)^2),  g = linspace(-1,1,8), h=2/7
//
// Output contract (derived R0-R4, verified): out = REAL plane only, (B,16) f32.
//
// GEMM-ified as (B x 1024) @ (1024 x 16) with mfma_f32_16x16x32_bf16; each
// lane's A-fragment is the 8 RBF values of ONE x scalar, computed straight
// into the fragment. x tile staged in LDS (pad 66). Coeffs pre-converted to
// bf16 in d_ws (32 KB, L1-resident).
//
// R6 changes (theory: main kernel is VALU-issue-bound around the exps):
//  - pack8 bit-twiddling (20 insts/step) -> native __bf16 casts; gfx950 has
//    v_cvt_pk_bf16_f32 and clang pairs the fptruncs (~4 insts/step).
//  - basis z / z*z as packed float2 -> v_pk_fma_f32 / v_pk_mul_f32 (16->8).
//  - dual MFMA accumulators (break the 32-deep serial acc chain), unroll 8.
//  - __launch_bounds__(256,4): pin 4 waves/SIMD (LDS caps blocks/CU at 4).

typedef __attribute__((ext_vector_type(8))) short  short8;
typedef __attribute__((ext_vector_type(4))) float  floatx4;
typedef __attribute__((ext_vector_type(2))) float  floatx2;
typedef __attribute__((ext_vector_type(8))) __bf16 bf16x8;

__device__ __forceinline__ float fexp2(float x) {
#if __has_builtin(__builtin_amdgcn_exp2f)
  return __builtin_amdgcn_exp2f(x);
#else
  return exp2f(x);
#endif
}

// ---- kernel 1: coeffs fp32 -> bf16 into ws (same [i][o][kc] layout) ----
__global__ void cvt_coeffs(const float* __restrict__ cre,
                           const float* __restrict__ cim,
                           uint16_t* __restrict__ w, int ncre, int ntot) {
  int idx = blockIdx.x * 256 + threadIdx.x;
  if (idx >= ntot) return;
  float v = (idx < ncre) ? cre[idx] : cim[idx - ncre];
  w[idx] = (uint16_t)((__float_as_uint(v) + 0x8000u) >> 16);
}

// ---- kernel 2: main fused basis + GEMM ----
// block = 256 threads = 4 waves; wave w handles rows [blk*64 + w*16, +16)
// K-loop: 32 steps of K=32 (i-pair per step); MODE 0: 1 MFMA/step (re only)
template <int MODE>
__global__ __launch_bounds__(256, 4)
void cvkan_main(const float* __restrict__ xre, const float* __restrict__ xim,
                const uint16_t* __restrict__ wbf,
                const float* __restrict__ bre, const float* __restrict__ bim,
                float* __restrict__ out, int out_size_elems) {
  __shared__ float ldsx[2 * 64 * 66];   // [mat][row<64][i pad 66] = 33792 B
  const int tid = threadIdx.x;
  const size_t b0 = (size_t)blockIdx.x * 64;

  // stage x tile (fully coalesced float4 reads; 2-way LDS write aliasing=free)
  {
    const float4* sre = (const float4*)(xre + b0 * 64);
    const float4* sim = (const float4*)(xim + b0 * 64);
#pragma unroll
    for (int j = 0; j < 4; ++j) {
      int e4  = tid + j * 256;          // float4 index in 64x64 tile
      int row = e4 >> 4;
      int col = (e4 & 15) * 4;
      float4 v = sre[e4];
      float* d = &ldsx[row * 66 + col];
      *(float2*)(d)     = make_float2(v.x, v.y);
      *(float2*)(d + 2) = make_float2(v.z, v.w);
      float4 u = sim[e4];
      float* d2 = d + 4224;             // 64*66
      *(float2*)(d2)     = make_float2(u.x, u.y);
      *(float2*)(d2 + 2) = make_float2(u.z, u.w);
    }
  }
  __syncthreads();

  const int lane = tid & 63;
  const int wave = tid >> 6;
  const int n  = lane & 15;   // A-row m within tile / B-col o / D-col
  const int q  = lane >> 4;   // quad
  const int qh = q >> 1;      // which i of the pair
  const int mt = q & 1;       // 0: re-basis half (kc 0..7), 1: im-basis half

  const float* xrow = &ldsx[mt * 4224 + (wave * 16 + n) * 66];
  const int wsoff = n * 16 + mt * 8;    // element offset inside W[i][o][kc]

  floatx4 accr0 = {0.f, 0.f, 0.f, 0.f};
  floatx4 accr1 = {0.f, 0.f, 0.f, 0.f};
  floatx4 acci0 = {0.f, 0.f, 0.f, 0.f};
  floatx4 acci1 = {0.f, 0.f, 0.f, 0.f};

  // exp(-((t-g)/h)^2) = exp2(-(fma(t,CS,NGA))^2), CS = (7/2)*sqrt(log2 e)
  constexpr float CS = 4.2039284307525743f;
  const floatx2 cs2 = {CS, CS};
  const floatx2 nga[4] = {
    {  CS,             CS * (5.f/7.f) },
    {  CS * (3.f/7.f), CS * (1.f/7.f) },
    { -CS * (1.f/7.f), -CS * (3.f/7.f) },
    { -CS * (5.f/7.f), -CS            }
  };

#pragma unroll 8
  for (int s = 0; s < 32; ++s) {
    const int i = 2 * s + qh;
    const float t = xrow[i];
    const floatx2 tt = {t, t};

    union { bf16x8 h; short8 s8; } cvt;
#pragma unroll
    for (int k = 0; k < 4; ++k) {
      floatx2 z = __builtin_elementwise_fma(tt, cs2, nga[k]); // v_pk_fma_f32
      floatx2 m = z * z;                                      // v_pk_mul_f32
      cvt.h[2 * k]     = (__bf16)fexp2(-m.x);   // neg folds into v_exp_f32
      cvt.h[2 * k + 1] = (__bf16)fexp2(-m.y);   // pair -> v_cvt_pk_bf16_f32
    }
    short8 af = cvt.s8;

    const uint16_t* wp = wbf + (size_t)i * 256 + wsoff;
    short8 br = *(const short8*)(wp);
    if (s & 1) accr1 = __builtin_amdgcn_mfma_f32_16x16x32_bf16(af, br, accr1, 0, 0, 0);
    else       accr0 = __builtin_amdgcn_mfma_f32_16x16x32_bf16(af, br, accr0, 0, 0, 0);
    if constexpr (MODE == 1) {
      short8 bi = *(const short8*)(wp + 16384);
      if (s & 1) acci1 = __builtin_amdgcn_mfma_f32_16x16x32_bf16(af, bi, acci1, 0, 0, 0);
      else       acci0 = __builtin_amdgcn_mfma_f32_16x16x32_bf16(af, bi, acci0, 0, 0, 0);
    }
  }

  const floatx4 accr = accr0 + accr1;

  // C/D layout: col = lane&15, row = (lane>>4)*4 + reg  [verified m89/m91]
  const float biasr = bre[n];
  const size_t rowbase = b0 + (size_t)wave * 16;
  const size_t lim = (size_t)out_size_elems;

  if constexpr (MODE == 0) {
    // real plane only: out[b*16 + o] = Re(y)
#pragma unroll
    for (int r = 0; r < 4; ++r) {
      const int row = q * 4 + r;
      const size_t idx = (rowbase + row) * 16 + n;
      if (idx < lim) out[idx] = accr[r] + biasr;
    }
  } else {
    // interleaved complex64 view: out[2*idx] = re, out[2*idx+1] = im
    const floatx4 acci = acci0 + acci1;
    const float biasi = bim[n];
#pragma unroll
    for (int r = 0; r < 4; ++r) {
      const int row = q * 4 + r;
      const size_t idx = (rowbase + row) * 16 + n;
      if (2 * idx + 1 < lim) {
        float2 v = make_float2(accr[r] + biasr, acci[r] + biasi);
        *(float2*)(out + 2 * idx) = v;
      }
    }
  }
}

extern "C" void kernel_launch(void* const* d_in, const int* in_sizes, int n_in,
                              void* d_out, int out_size, void* d_ws, size_t ws_size,
                              hipStream_t stream) {
  const float* xre = (const float*)d_in[0];
  const float* xim = (const float*)d_in[1];
  const float* cre = (const float*)d_in[2];
  const float* cim = (const float*)d_in[3];
  const float* bre = (const float*)d_in[4];
  const float* bim = (const float*)d_in[5];
  float* out = (float*)d_out;

  const long long Bn = in_sizes[0] / 64;   // batch rows (65536)
  const int grid = (int)(Bn / 64);         // 64 rows per block

  const int ncre = in_sizes[2];            // 16384
  const int ntot = ncre + in_sizes[3];     // 32768

  // mode 1 (interleaved complex) only if the buffer provably holds 2 f32
  // per output element; otherwise mode 0 (real plane only).  [R4: mode 0]
  const int mode = ((long long)out_size >= Bn * 32) ? 1 : 0;

  uint16_t* w = (uint16_t*)d_ws;
  const int ncvt = (mode == 1) ? ntot : ncre;   // mode 0: re coeffs only
  cvt_coeffs<<<(ncvt + 255) / 256, 256, 0, stream>>>(cre, cim, w, ncre, ncvt);
  if (mode == 0) {
    cvkan_main<0><<<grid, 256, 0, stream>>>(xre, xim, w, bre, bim, out, out_size);
  } else {
    cvkan_main<1><<<grid, 256, 0, stream>>>(xre, xim, w, bre, bim, out, out_size);
  }
}

// Round 2
// 94.430 us; speedup vs baseline: 1.0526x; 1.0526x over previous
//
#include <hip/hip_runtime.h>
#include <stdint.h>

// CVKAN layer: out[b,o] = Re( sum_{i,k} basis[b,i,k] * coeffs[i,o,k] + bias[o] )
// basis k<8  = exp(-((x_re[b,i]-g_k)/h)^2), k>=8 uses x_im; g=linspace(-1,1,8), h=2/7
// Output contract (derived R0-R4, verified): out = REAL plane only, (B,16) f32.
//
// R7: single fused kernel.
//  - K-order permuted to [re-half (i=0..63)][im-half (i=0..63)], 8 kc each.
//    Per MFMA step s, quad q handles i=4s+q -> the 4 lanes of a quad read 4
//    CONSECUTIVE x floats (16B coalesced); x comes straight from global (L1)
//    inside the loop -- no x LDS staging, no whole-grid load phase.
//  - coeff table (re plane, 16K coeffs) converted f32->bf16 per block into
//    32 KB LDS, layout [half][i][o][8]; B-frags via ds_read_b128 (uniform
//    8-access/bank = b128 minimum, conflict-neutral). L1 now holds only x.
//  - R6 spill suspects reverted: pack8, scalar basis math, single acc chain,
//    unroll 4, plain __launch_bounds__(256). (R6: WRITE_SIZE 15.4MB vs 4.2MB
//    ideal = scratch spill; VALUBusy 0.97% = vmcnt stall.)

typedef __attribute__((ext_vector_type(8))) short  short8;
typedef __attribute__((ext_vector_type(4))) float  floatx4;

__device__ __forceinline__ float fexp2(float x) {
#if __has_builtin(__builtin_amdgcn_exp2f)
  return __builtin_amdgcn_exp2f(x);
#else
  return exp2f(x);
#endif
}

// pack 8 f32 -> 8 bf16 (round-half-up; error << threshold)
__device__ __forceinline__ short8 pack8(const float* e) {
  union { unsigned int u[4]; short8 s; } c;
#pragma unroll
  for (int k = 0; k < 4; ++k) {
    unsigned lo = (__float_as_uint(e[2 * k])     + 0x8000u) >> 16;
    unsigned hi = (__float_as_uint(e[2 * k + 1]) + 0x8000u) & 0xffff0000u;
    c.u[k] = hi | lo;
  }
  return c.s;
}

// block = 256 threads = 4 waves; wave w -> rows [blk*64 + w*16, +16)
// 32 MFMA steps of K=32: steps 0..15 re-half (x_re), 16..31 im-half (x_im).
template <int MODE>
__global__ __launch_bounds__(256)
void cvkan_main(const float* __restrict__ xre, const float* __restrict__ xim,
                const float* __restrict__ cre, const float* __restrict__ cim,
                const float* __restrict__ bre, const float* __restrict__ bim,
                float* __restrict__ out, int out_size_elems) {
  // [half][i][o][kc]: half*8192 + i*128 + o*8 + kc   (uint16 units, 32 KB)
  __shared__ uint16_t wlds[16384];
  const int tid = threadIdx.x;
  const size_t b0 = (size_t)blockIdx.x * 64;

  // ---- stage+convert re-plane coeffs: 64 KB f32 -> 32 KB bf16 in LDS ----
  // src layout [i][o][k(16)]; each float4 (k0..k0+3) lands contiguously at
  // [k0>>3][i][o][k0&7]. Coalesced float4 reads; uniform-4/bank ds writes.
  {
    const float4* cf = (const float4*)cre;
#pragma unroll
    for (int it = 0; it < 16; ++it) {
      const int idx = it * 1024 + tid * 4;       // element index, 16384 total
      const float4 v = cf[it * 256 + tid];
      const int i = idx >> 8, o = (idx >> 4) & 15, k0 = idx & 15;
      const int dst = ((k0 >> 3) << 13) + i * 128 + o * 8 + (k0 & 7);
      unsigned lo = ((__float_as_uint(v.x) + 0x8000u) >> 16) |
                    ((__float_as_uint(v.y) + 0x8000u) & 0xffff0000u);
      unsigned hi = ((__float_as_uint(v.z) + 0x8000u) >> 16) |
                    ((__float_as_uint(v.w) + 0x8000u) & 0xffff0000u);
      *(uint2*)&wlds[dst] = make_uint2(lo, hi);
    }
  }
  __syncthreads();

  const int lane = tid & 63;
  const int wave = tid >> 6;
  const int n  = lane & 15;   // A-row m within tile / B-col o / D-col
  const int q  = lane >> 4;   // quad: i = 4s + q

  const size_t row = b0 + (size_t)(wave * 16 + n);
  const float* xr = xre + row * 64 + q;     // t = xr[4*s]
  const float* xi = xim + row * 64 + q;

  floatx4 accr = {0.f, 0.f, 0.f, 0.f};
  floatx4 acci = {0.f, 0.f, 0.f, 0.f};

  // exp(-((t-g)/h)^2) = exp2(-(fma(t,CS,NGA))^2), CS = (7/2)*sqrt(log2 e)
  constexpr float CS = 4.2039284307525743f;
  const float NGA[8] = {  CS,            CS * (5.f/7.f),  CS * (3.f/7.f),
                          CS * (1.f/7.f), -CS * (1.f/7.f), -CS * (3.f/7.f),
                         -CS * (5.f/7.f), -CS };

  // ---- half 0: re basis (kc 0..7) driven by x_re ----
#pragma unroll 4
  for (int s = 0; s < 16; ++s) {
    const float t = xr[4 * s];
    float e[8];
#pragma unroll
    for (int k = 0; k < 8; ++k) {
      float z = fmaf(t, CS, NGA[k]);
      e[k] = fexp2(-(z * z));
    }
    const short8 af = pack8(e);
    const int i = 4 * s + q;
    const short8 br = *(const short8*)&wlds[i * 128 + n * 8];
    accr = __builtin_amdgcn_mfma_f32_16x16x32_bf16(af, br, accr, 0, 0, 0);
    if constexpr (MODE == 1) {
      float c8[8];
      *(float4*)(c8)     = *(const float4*)(cim + (i * 16 + n) * 16);
      *(float4*)(c8 + 4) = *(const float4*)(cim + (i * 16 + n) * 16 + 4);
      const short8 bi = pack8(c8);
      acci = __builtin_amdgcn_mfma_f32_16x16x32_bf16(af, bi, acci, 0, 0, 0);
    }
  }

  // ---- half 1: im basis (kc 8..15) driven by x_im ----
#pragma unroll 4
  for (int s = 0; s < 16; ++s) {
    const float t = xi[4 * s];
    float e[8];
#pragma unroll
    for (int k = 0; k < 8; ++k) {
      float z = fmaf(t, CS, NGA[k]);
      e[k] = fexp2(-(z * z));
    }
    const short8 af = pack8(e);
    const int i = 4 * s + q;
    const short8 br = *(const short8*)&wlds[8192 + i * 128 + n * 8];
    accr = __builtin_amdgcn_mfma_f32_16x16x32_bf16(af, br, accr, 0, 0, 0);
    if constexpr (MODE == 1) {
      float c8[8];
      *(float4*)(c8)     = *(const float4*)(cim + (i * 16 + n) * 16 + 8);
      *(float4*)(c8 + 4) = *(const float4*)(cim + (i * 16 + n) * 16 + 12);
      const short8 bi = pack8(c8);
      acci = __builtin_amdgcn_mfma_f32_16x16x32_bf16(af, bi, acci, 0, 0, 0);
    }
  }

  // C/D layout: col = lane&15, row = (lane>>4)*4 + reg  [verified m89/m91]
  const float biasr = bre[n];
  const size_t rowbase = b0 + (size_t)wave * 16;
  const size_t lim = (size_t)out_size_elems;

  if constexpr (MODE == 0) {
#pragma unroll
    for (int r = 0; r < 4; ++r) {
      const int rw = q * 4 + r;
      const size_t idx = (rowbase + rw) * 16 + n;
      if (idx < lim) out[idx] = accr[r] + biasr;
    }
  } else {
    const float biasi = bim[n];
#pragma unroll
    for (int r = 0; r < 4; ++r) {
      const int rw = q * 4 + r;
      const size_t idx = (rowbase + rw) * 16 + n;
      if (2 * idx + 1 < lim) {
        float2 v = make_float2(accr[r] + biasr, acci[r] + biasi);
        *(float2*)(out + 2 * idx) = v;
      }
    }
  }
}

extern "C" void kernel_launch(void* const* d_in, const int* in_sizes, int n_in,
                              void* d_out, int out_size, void* d_ws, size_t ws_size,
                              hipStream_t stream) {
  const float* xre = (const float*)d_in[0];
  const float* xim = (const float*)d_in[1];
  const float* cre = (const float*)d_in[2];
  const float* cim = (const float*)d_in[3];
  const float* bre = (const float*)d_in[4];
  const float* bim = (const float*)d_in[5];
  float* out = (float*)d_out;

  const long long Bn = in_sizes[0] / 64;   // batch rows (65536)
  const int grid = (int)(Bn / 64);         // 64 rows per block

  // mode 1 (interleaved complex) only if the buffer provably holds 2 f32
  // per output element; otherwise mode 0 (real plane only).  [R4: mode 0]
  const int mode = ((long long)out_size >= Bn * 32) ? 1 : 0;

  if (mode == 0) {
    cvkan_main<0><<<grid, 256, 0, stream>>>(xre, xim, cre, cim, bre, bim, out, out_size);
  } else {
    cvkan_main<1><<<grid, 256, 0, stream>>>(xre, xim, cre, cim, bre, bim, out, out_size);
  }
}